// Round 12
// baseline (19741.728 us; speedup 1.0000x reference)
//
#include <hip/hip_runtime.h>

typedef short bf16x8 __attribute__((ext_vector_type(8)));
typedef float f32x4 __attribute__((ext_vector_type(4)));

static constexpr int kT  = 256;
static constexpr int kNU = 64;
static constexpr int kNX = 128;
static constexpr int kNY = 16;
static constexpr int kBT = 16;   // batch rows per block

// packed weight region sizes (elements)
static constexpr int kW1P = 64 * 6 * 64 * 8;   // 196608
static constexpr int kW2P = 8 * 32 * 64 * 8;   // 131072
static constexpr int kCP  = 4 * 64 * 8;        // 2048
static constexpr int kDP  = 2 * 64 * 8;        // 1024
static constexpr int kPackTotal = kW1P + kW2P + kCP + kDP; // 330752

__device__ __forceinline__ unsigned short f2bf(float f) {
  union { float f; unsigned int u; } v; v.f = f;
  unsigned int r = v.u + 0x7fffu + ((v.u >> 16) & 1u);   // RNE to bf16
  return (unsigned short)(r >> 16);
}

// Pack W1/W2/C/D (fp32) into bf16 MFMA B-fragment order:
// frag index (n, ks, lane, j) holds W[16n + (lane&15)][32ks + 8*(lane>>4) + j]
__global__ __launch_bounds__(256)
void prepack_kernel(const float* __restrict__ W1, const float* __restrict__ W2,
                    const float* __restrict__ C, const float* __restrict__ D,
                    unsigned short* __restrict__ wp) {
  int i = blockIdx.x * 256 + threadIdx.x;
  if (i >= kPackTotal) return;
  float v;
  if (i < kW1P) {
    int j = i & 7, l = (i >> 3) & 63, t = i >> 9;
    int ks = t % 6, n = t / 6;
    v = W1[(16 * n + (l & 15)) * 192 + 32 * ks + 8 * (l >> 4) + j];
  } else if (i < kW1P + kW2P) {
    int k = i - kW1P;
    int j = k & 7, l = (k >> 3) & 63, t = k >> 9;
    int ks = t & 31, n = t >> 5;
    v = W2[(16 * n + (l & 15)) * 1024 + 32 * ks + 8 * (l >> 4) + j];
  } else if (i < kW1P + kW2P + kCP) {
    int k = i - (kW1P + kW2P);
    int j = k & 7, l = (k >> 3) & 63, ks = k >> 9;
    v = C[(l & 15) * 128 + 32 * ks + 8 * (l >> 4) + j];
  } else {
    int k = i - (kW1P + kW2P + kCP);
    int j = k & 7, l = (k >> 3) & 63, ks = k >> 9;
    v = D[(l & 15) * 64 + 32 * ks + 8 * (l >> 4) + j];
  }
  wp[i] = f2bf(v);
}

// RK45 stage-combination coefficients (dt folded in), row e = coeffs for z of stage e+2
__constant__ float CTc[5][5] = {
  {(float)(0.01 / 4.0), 0.f, 0.f, 0.f, 0.f},
  {(float)(0.01 * 3.0 / 32.0), (float)(0.01 * 9.0 / 32.0), 0.f, 0.f, 0.f},
  {(float)(0.01 * 1932.0 / 2197.0), (float)(-0.01 * 7200.0 / 2197.0), (float)(0.01 * 7296.0 / 2197.0), 0.f, 0.f},
  {(float)(0.01 * 439.0 / 216.0), (float)(-0.01 * 8.0), (float)(0.01 * 3680.0 / 513.0), (float)(-0.01 * 845.0 / 4104.0), 0.f},
  {(float)(-0.01 * 8.0 / 27.0), (float)(0.01 * 2.0), (float)(-0.01 * 3544.0 / 2565.0), (float)(0.01 * 1859.0 / 4104.0), (float)(-0.01 * 11.0 / 40.0)}
};

// tanh(x) = 1 - 2/(exp2(2x*log2 e)+1)
__device__ __forceinline__ float tanh_fast(float x) {
  float t = exp2f(x * 2.8853900817779268f);
  return 1.0f - 2.0f * __builtin_amdgcn_rcpf(t + 1.0f);
}

#define MFMA_BF16(A, B, C) __builtin_amdgcn_mfma_f32_16x16x32_bf16(A, B, C, 0, 0, 0)
#define BARRIER_LGKM do { asm volatile("s_waitcnt lgkmcnt(0)" ::: "memory"); \
                          __builtin_amdgcn_s_barrier(); } while (0)

// One block = 16 batch rows, 4 waves (1/SIMD, 512-VGPR budget).
// Weights stream global->VGPR through 4 named groups x 4 frags (64 VGPR),
// distance-2 software pipeline; cross-phase tail prefetch (global loads pass
// the lgkm-only barriers). Compiler inserts exact vmcnt waits. No weight LDS.
// Per wave: mm1 = 16 NH tiles, mm2 = 2 NX col-tiles, u-pass = 16 ubias tiles.
__global__ __launch_bounds__(256, 1)
void rk45_kernel(const float* __restrict__ u, const float* __restrict__ x0,
                 const float* __restrict__ b1g, const float* __restrict__ b2g,
                 const unsigned short* __restrict__ wp,
                 float* __restrict__ Xout, float* __restrict__ Yout) {
  __shared__ __align__(16) unsigned short zs[16][232];   // z = [x | u] bf16
  __shared__ __align__(16) unsigned short hs[16][1048];  // h bf16 (16 x 1024)
  __shared__ __align__(16) float xs[16][132];            // master state fp32
  __shared__ __align__(16) unsigned short cdl[384][8];   // C/D fragment table (6KB)

  const int tid  = threadIdx.x;
  const int lane = tid & 63;
  const int w    = tid >> 6;     // wave 0..3
  const int r16  = lane & 15;
  const int g    = lane >> 4;    // 0..3
  const int b0   = blockIdx.x * kBT;
  const int colA = 32 * w + r16;        // mm2 col-tile 2w
  const int colB = 32 * w + 16 + r16;   // mm2 col-tile 2w+1

  const bf16x8* W1P = (const bf16x8*)wp;
  const bf16x8* W2P = (const bf16x8*)(wp + kW1P);

// fragment accessors (all indices compile-time after unroll)
#define W1XF(NT, KS) W1P[((16 * w + (NT)) * 6 + (KS)) * 64 + lane]
#define W1UF(NT, J)  W1P[((16 * w + (NT)) * 6 + 4 + (J)) * 64 + lane]
#define W2F(CT, KS)  W2P[((2 * w + (CT)) * 32 + (KS)) * 64 + lane]

// group loads into 4 named frag registers
#define LDG_U(F0, F1, F2, F3, I)  do { F0 = W1UF(2*(I), 0); F1 = W1UF(2*(I), 1); \
                                       F2 = W1UF(2*(I)+1, 0); F3 = W1UF(2*(I)+1, 1); } while (0)
#define LDG_1(F0, F1, F2, F3, NT) do { F0 = W1XF(NT, 0); F1 = W1XF(NT, 1); \
                                       F2 = W1XF(NT, 2); F3 = W1XF(NT, 3); } while (0)
#define LDG_2(F0, F1, F2, F3, J)  do { F0 = W2F(0, 2*(J)); F1 = W2F(0, 2*(J)+1); \
                                       F2 = W2F(1, 2*(J)); F3 = W2F(1, 2*(J)+1); } while (0)

  // C/D fragments -> LDS table (wave-0 Y-pass reads via lgkm only)
  {
    if (tid < 384) *(bf16x8*)&cdl[tid][0] = ((const bf16x8*)(wp + kW1P + kW2P))[tid];
    int t2 = tid + 256;
    if (t2 < 384) *(bf16x8*)&cdl[t2][0] = ((const bf16x8*)(wp + kW1P + kW2P))[t2];
  }

  float b1r[16];
  #pragma unroll
  for (int nt = 0; nt < 16; ++nt)
    b1r[nt] = b1g[256 * w + 16 * nt + r16];
  const float b2A = b2g[colA];
  const float b2B = b2g[colB];

  float xrA[4], xrB[4];
  f32x4 ubias[16];
  f32x4 k1A = {0,0,0,0}, k2A = {0,0,0,0}, k3A = {0,0,0,0}, k4A = {0,0,0,0}, k5A = {0,0,0,0};
  f32x4 k1B = {0,0,0,0}, k2B = {0,0,0,0}, k3B = {0,0,0,0}, k4B = {0,0,0,0}, k5B = {0,0,0,0};

  #pragma unroll
  for (int q = 0; q < 4; ++q) {
    int row = 4 * g + q;
    float xa = x0[(b0 + row) * kNX + colA];
    float xb = x0[(b0 + row) * kNX + colB];
    xrA[q] = xa; xrB[q] = xb;
    xs[row][colA] = xa; xs[row][colB] = xb;
    zs[row][colA] = f2bf(xa); zs[row][colB] = f2bf(xb);
  }

  // u prefetch (one step ahead): 4 elems/thread
  const int urow = tid >> 4, ucol = (tid & 15) * 4;
  float4 ureg = *(const float4*)&u[((b0 + urow) * kT + 0) * kNU + ucol];

  // weight pipeline registers: 4 groups x 4 frags
  bf16x8 g0f0, g0f1, g0f2, g0f3;
  bf16x8 g1f0, g1f1, g1f2, g1f3;
  bf16x8 g2f0, g2f1, g2f2, g2f3;
  bf16x8 g3f0, g3f1, g3f2, g3f3;

  // prologue: prime u-pass groups 0,1
  LDG_U(g0f0, g0f1, g0f2, g0f3, 0);
  LDG_U(g1f0, g1f1, g1f2, g1f3, 1);
  __syncthreads();

  const float D1 = (float)(0.01 * 16.0 / 135.0);
  const float D3 = (float)(0.01 * 6656.0 / 12825.0);
  const float D4 = (float)(0.01 * 28561.0 / 56430.0);
  const float D5 = (float)(-0.01 * 9.0 / 50.0);
  const float D6 = (float)(0.01 * 2.0 / 55.0);

  #pragma unroll 1
  for (int t = 0; t < kT; ++t) {
    // ---- stage A: write X[t] from xs (coalesced), commit u_t, prefetch u_{t+1}
    {
      int row = tid >> 4, col = (tid & 15) * 8;
      float4 xv0 = *(const float4*)&xs[row][col];
      float4 xv1 = *(const float4*)&xs[row][col + 4];
      *(float4*)&Xout[((b0 + row) * kT + t) * kNX + col] = xv0;
      *(float4*)&Xout[((b0 + row) * kT + t) * kNX + col + 4] = xv1;
      zs[urow][kNX + ucol]     = f2bf(ureg.x);
      zs[urow][kNX + ucol + 1] = f2bf(ureg.y);
      zs[urow][kNX + ucol + 2] = f2bf(ureg.z);
      zs[urow][kNX + ucol + 3] = f2bf(ureg.w);
      if (t + 1 < kT)
        ureg = *(const float4*)&u[((b0 + urow) * kT + (t + 1)) * kNU + ucol];
    }
    BARRIER_LGKM;

    // ---- u-pass (once per step): ubias[nt] = W1u-slice @ u_t + b1, 8 group-iters
    {
      bf16x8 zu0 = *(const bf16x8*)&zs[r16][8 * g + 128];
      bf16x8 zu1 = *(const bf16x8*)&zs[r16][8 * g + 160];
#define UPASS(I, F0, F1, F2, F3, I0_, I1_, ISS)                                \
      { ISS;                                                                   \
        float bv0 = b1r[2*(I)], bv1 = b1r[2*(I)+1];                            \
        f32x4 ua = {bv0, bv0, bv0, bv0}, ub = {bv1, bv1, bv1, bv1};            \
        ua = MFMA_BF16(zu0, F0, ua); ua = MFMA_BF16(zu1, F1, ua);              \
        ub = MFMA_BF16(zu0, F2, ub); ub = MFMA_BF16(zu1, F3, ub);              \
        ubias[2*(I)] = ua; ubias[2*(I)+1] = ub; }
      UPASS(0, g0f0, g0f1, g0f2, g0f3, 0, 1, LDG_U(g2f0, g2f1, g2f2, g2f3, 2))
      UPASS(1, g1f0, g1f1, g1f2, g1f3, 2, 3, LDG_U(g3f0, g3f1, g3f2, g3f3, 3))
      UPASS(2, g2f0, g2f1, g2f2, g2f3, 4, 5, LDG_U(g0f0, g0f1, g0f2, g0f3, 4))
      UPASS(3, g3f0, g3f1, g3f2, g3f3, 6, 7, LDG_U(g1f0, g1f1, g1f2, g1f3, 5))
      UPASS(4, g0f0, g0f1, g0f2, g0f3, 8, 9, LDG_U(g2f0, g2f1, g2f2, g2f3, 6))
      UPASS(5, g1f0, g1f1, g1f2, g1f3, 10, 11, LDG_U(g3f0, g3f1, g3f2, g3f3, 7))
      UPASS(6, g2f0, g2f1, g2f2, g2f3, 12, 13, LDG_1(g0f0, g0f1, g0f2, g0f3, 0))
      UPASS(7, g3f0, g3f1, g3f2, g3f3, 14, 15, LDG_1(g1f0, g1f1, g1f2, g1f3, 1))
#undef UPASS
    }

    #pragma unroll 1
    for (int e = 0; e < 6; ++e) {
      // ---- matmul1: h = tanh(x-part @ W1x^T + ubias); wave w owns NH [256w, 256w+256)
      bf16x8 za0 = *(const bf16x8*)&zs[r16][8 * g + 0];
      bf16x8 za1 = *(const bf16x8*)&zs[r16][8 * g + 32];
      bf16x8 za2 = *(const bf16x8*)&zs[r16][8 * g + 64];
      bf16x8 za3 = *(const bf16x8*)&zs[r16][8 * g + 96];

#define MM1(NT, F0, F1, F2, F3, ISS)                                           \
      { ISS;                                                                   \
        f32x4 aa = {0,0,0,0}, ab = {0,0,0,0};                                  \
        aa = MFMA_BF16(za0, F0, aa); ab = MFMA_BF16(za1, F1, ab);              \
        aa = MFMA_BF16(za2, F2, aa); ab = MFMA_BF16(za3, F3, ab);              \
        int n = 16 * w + (NT);                                                 \
        _Pragma("unroll")                                                      \
        for (int q = 0; q < 4; ++q) {                                          \
          float hv = tanh_fast(aa[q] + ab[q] + ubias[NT][q]);                  \
          hs[4 * g + q][16 * n + r16] = f2bf(hv);                              \
        } }
      MM1(0,  g0f0, g0f1, g0f2, g0f3, LDG_1(g2f0, g2f1, g2f2, g2f3, 2))
      MM1(1,  g1f0, g1f1, g1f2, g1f3, LDG_1(g3f0, g3f1, g3f2, g3f3, 3))
      MM1(2,  g2f0, g2f1, g2f2, g2f3, LDG_1(g0f0, g0f1, g0f2, g0f3, 4))
      MM1(3,  g3f0, g3f1, g3f2, g3f3, LDG_1(g1f0, g1f1, g1f2, g1f3, 5))
      MM1(4,  g0f0, g0f1, g0f2, g0f3, LDG_1(g2f0, g2f1, g2f2, g2f3, 6))
      MM1(5,  g1f0, g1f1, g1f2, g1f3, LDG_1(g3f0, g3f1, g3f2, g3f3, 7))
      MM1(6,  g2f0, g2f1, g2f2, g2f3, LDG_1(g0f0, g0f1, g0f2, g0f3, 8))
      MM1(7,  g3f0, g3f1, g3f2, g3f3, LDG_1(g1f0, g1f1, g1f2, g1f3, 9))
      MM1(8,  g0f0, g0f1, g0f2, g0f3, LDG_1(g2f0, g2f1, g2f2, g2f3, 10))
      MM1(9,  g1f0, g1f1, g1f2, g1f3, LDG_1(g3f0, g3f1, g3f2, g3f3, 11))
      MM1(10, g2f0, g2f1, g2f2, g2f3, LDG_1(g0f0, g0f1, g0f2, g0f3, 12))
      MM1(11, g3f0, g3f1, g3f2, g3f3, LDG_1(g1f0, g1f1, g1f2, g1f3, 13))
      MM1(12, g0f0, g0f1, g0f2, g0f3, LDG_1(g2f0, g2f1, g2f2, g2f3, 14))
      MM1(13, g1f0, g1f1, g1f2, g1f3, LDG_1(g3f0, g3f1, g3f2, g3f3, 15))
      MM1(14, g2f0, g2f1, g2f2, g2f3, LDG_2(g0f0, g0f1, g0f2, g0f3, 0))
      MM1(15, g3f0, g3f1, g3f2, g3f3, LDG_2(g1f0, g1f1, g1f2, g1f3, 1))
#undef MM1

      if (e == 0 && w == 0) {
        // y_t = x C^T + u D^T from the LDS C/D table (lgkm loads only)
        bf16x8 zu0 = *(const bf16x8*)&zs[r16][8 * g + 128];
        bf16x8 zu1 = *(const bf16x8*)&zs[r16][8 * g + 160];
        f32x4 ay = {0,0,0,0};
        ay = MFMA_BF16(za0, *(const bf16x8*)&cdl[0 * 64 + lane][0], ay);
        ay = MFMA_BF16(za1, *(const bf16x8*)&cdl[1 * 64 + lane][0], ay);
        ay = MFMA_BF16(za2, *(const bf16x8*)&cdl[2 * 64 + lane][0], ay);
        ay = MFMA_BF16(za3, *(const bf16x8*)&cdl[3 * 64 + lane][0], ay);
        ay = MFMA_BF16(zu0, *(const bf16x8*)&cdl[4 * 64 + lane][0], ay);
        ay = MFMA_BF16(zu1, *(const bf16x8*)&cdl[5 * 64 + lane][0], ay);
        #pragma unroll
        for (int q = 0; q < 4; ++q)
          Yout[((b0 + 4 * g + q) * kT + t) * kNY + r16] = ay[q];
      }
      BARRIER_LGKM;   // hs visible; weight loads stay in flight

      // ---- matmul2: k = h @ W2^T + b2; wave w owns NX cols [32w, 32w+32)
      f32x4 kaA = {0,0,0,0}, kbA = {0,0,0,0}, kaB = {0,0,0,0}, kbB = {0,0,0,0};
#define MM2(J, F0, F1, F2, F3, ISS)                                            \
      { ISS;                                                                   \
        bf16x8 h0 = *(const bf16x8*)&hs[r16][8 * g + 32 * (2 * (J))];          \
        bf16x8 h1 = *(const bf16x8*)&hs[r16][8 * g + 32 * (2 * (J) + 1)];      \
        kaA = MFMA_BF16(h0, F0, kaA); kbA = MFMA_BF16(h1, F1, kbA);            \
        kaB = MFMA_BF16(h0, F2, kaB); kbB = MFMA_BF16(h1, F3, kbB); }
      MM2(0,  g0f0, g0f1, g0f2, g0f3, LDG_2(g2f0, g2f1, g2f2, g2f3, 2))
      MM2(1,  g1f0, g1f1, g1f2, g1f3, LDG_2(g3f0, g3f1, g3f2, g3f3, 3))
      MM2(2,  g2f0, g2f1, g2f2, g2f3, LDG_2(g0f0, g0f1, g0f2, g0f3, 4))
      MM2(3,  g3f0, g3f1, g3f2, g3f3, LDG_2(g1f0, g1f1, g1f2, g1f3, 5))
      MM2(4,  g0f0, g0f1, g0f2, g0f3, LDG_2(g2f0, g2f1, g2f2, g2f3, 6))
      MM2(5,  g1f0, g1f1, g1f2, g1f3, LDG_2(g3f0, g3f1, g3f2, g3f3, 7))
      MM2(6,  g2f0, g2f1, g2f2, g2f3, LDG_2(g0f0, g0f1, g0f2, g0f3, 8))
      MM2(7,  g3f0, g3f1, g3f2, g3f3, LDG_2(g1f0, g1f1, g1f2, g1f3, 9))
      MM2(8,  g0f0, g0f1, g0f2, g0f3, LDG_2(g2f0, g2f1, g2f2, g2f3, 10))
      MM2(9,  g1f0, g1f1, g1f2, g1f3, LDG_2(g3f0, g3f1, g3f2, g3f3, 11))
      MM2(10, g2f0, g2f1, g2f2, g2f3, LDG_2(g0f0, g0f1, g0f2, g0f3, 12))
      MM2(11, g3f0, g3f1, g3f2, g3f3, LDG_2(g1f0, g1f1, g1f2, g1f3, 13))
      MM2(12, g0f0, g0f1, g0f2, g0f3, LDG_2(g2f0, g2f1, g2f2, g2f3, 14))
      MM2(13, g1f0, g1f1, g1f2, g1f3, LDG_2(g3f0, g3f1, g3f2, g3f3, 15))
      if (e < 5) {
        MM2(14, g2f0, g2f1, g2f2, g2f3, LDG_1(g0f0, g0f1, g0f2, g0f3, 0))
        MM2(15, g3f0, g3f1, g3f2, g3f3, LDG_1(g1f0, g1f1, g1f2, g1f3, 1))
      } else {
        MM2(14, g2f0, g2f1, g2f2, g2f3, LDG_U(g0f0, g0f1, g0f2, g0f3, 0))
        MM2(15, g3f0, g3f1, g3f2, g3f3, LDG_U(g1f0, g1f1, g1f2, g1f3, 1))
      }
#undef MM2

      f32x4 kvA = kaA + kbA, kvB = kaB + kbB;
      #pragma unroll
      for (int q = 0; q < 4; ++q) { kvA[q] += b2A; kvB[q] += b2B; }

      if      (e == 0) { k1A = kvA; k1B = kvB; }
      else if (e == 1) { k2A = kvA; k2B = kvB; }
      else if (e == 2) { k3A = kvA; k3B = kvB; }
      else if (e == 3) { k4A = kvA; k4B = kvB; }
      else if (e == 4) { k5A = kvA; k5B = kvB; }

      if (e < 5) {
        float c1 = CTc[e][0], c2 = CTc[e][1], c3 = CTc[e][2], c4 = CTc[e][3], c5 = CTc[e][4];
        #pragma unroll
        for (int q = 0; q < 4; ++q) {
          float xtA = xrA[q] + c1 * k1A[q] + c2 * k2A[q] + c3 * k3A[q] + c4 * k4A[q] + c5 * k5A[q];
          float xtB = xrB[q] + c1 * k1B[q] + c2 * k2B[q] + c3 * k3B[q] + c4 * k4B[q] + c5 * k5B[q];
          zs[4 * g + q][colA] = f2bf(xtA);
          zs[4 * g + q][colB] = f2bf(xtB);
        }
      } else {
        #pragma unroll
        for (int q = 0; q < 4; ++q) {
          float xnA = xrA[q] + (D1 * k1A[q] + D3 * k3A[q] + D4 * k4A[q] + D5 * k5A[q] + D6 * kvA[q]);
          float xnB = xrB[q] + (D1 * k1B[q] + D3 * k3B[q] + D4 * k4B[q] + D5 * k5B[q] + D6 * kvB[q]);
          xrA[q] = xnA; xrB[q] = xnB;
          xs[4 * g + q][colA] = xnA; xs[4 * g + q][colB] = xnB;
          zs[4 * g + q][colA] = f2bf(xnA); zs[4 * g + q][colB] = f2bf(xnB);
        }
      }
      BARRIER_LGKM;   // zs ready for next stage's mm1
    }
  }
}

extern "C" void kernel_launch(void* const* d_in, const int* in_sizes, int n_in,
                              void* d_out, int out_size, void* d_ws, size_t ws_size,
                              hipStream_t stream) {
  const float* u  = (const float*)d_in[0];
  const float* x0 = (const float*)d_in[1];
  const float* W1 = (const float*)d_in[2];
  const float* b1 = (const float*)d_in[3];
  const float* W2 = (const float*)d_in[4];
  const float* b2 = (const float*)d_in[5];
  const float* C  = (const float*)d_in[6];
  const float* D  = (const float*)d_in[7];

  unsigned short* wp = (unsigned short*)d_ws;
  float* Xout = (float*)d_out;
  float* Yout = Xout + (size_t)512 * 256 * 128;

  hipLaunchKernelGGL(prepack_kernel, dim3((kPackTotal + 255) / 256), dim3(256), 0, stream,
                     W1, W2, C, D, wp);
  hipLaunchKernelGGL(rk45_kernel, dim3(32), dim3(256), 0, stream,
                     u, x0, b1, b2, (const unsigned short*)wp, Xout, Yout);
}

// Round 16
// 10920.037 us; speedup vs baseline: 1.8078x; 1.8078x over previous
//
#include <hip/hip_runtime.h>

typedef short bf16x8 __attribute__((ext_vector_type(8)));
typedef float f32x4 __attribute__((ext_vector_type(4)));

static constexpr int kT  = 256;
static constexpr int kNU = 64;
static constexpr int kNX = 128;
static constexpr int kNY = 16;
static constexpr int kBT = 16;   // batch rows per block

// packed weight region sizes (elements)
static constexpr int kW1P = 64 * 6 * 64 * 8;   // 196608
static constexpr int kW2P = 8 * 32 * 64 * 8;   // 131072
static constexpr int kCP  = 4 * 64 * 8;        // 2048
static constexpr int kDP  = 2 * 64 * 8;        // 1024
static constexpr int kPackTotal = kW1P + kW2P + kCP + kDP; // 330752

__device__ __forceinline__ unsigned short f2bf(float f) {
  union { float f; unsigned int u; } v; v.f = f;
  unsigned int r = v.u + 0x7fffu + ((v.u >> 16) & 1u);   // RNE to bf16
  return (unsigned short)(r >> 16);
}

// Pack W1/W2/C/D (fp32) into bf16 MFMA B-fragment order:
// frag index (n, ks, lane, j) holds W[16n + (lane&15)][32ks + 8*(lane>>4) + j]
__global__ __launch_bounds__(256)
void prepack_kernel(const float* __restrict__ W1, const float* __restrict__ W2,
                    const float* __restrict__ C, const float* __restrict__ D,
                    unsigned short* __restrict__ wp) {
  int i = blockIdx.x * 256 + threadIdx.x;
  if (i >= kPackTotal) return;
  float v;
  if (i < kW1P) {
    int j = i & 7, l = (i >> 3) & 63, t = i >> 9;
    int ks = t % 6, n = t / 6;
    v = W1[(16 * n + (l & 15)) * 192 + 32 * ks + 8 * (l >> 4) + j];
  } else if (i < kW1P + kW2P) {
    int k = i - kW1P;
    int j = k & 7, l = (k >> 3) & 63, t = k >> 9;
    int ks = t & 31, n = t >> 5;
    v = W2[(16 * n + (l & 15)) * 1024 + 32 * ks + 8 * (l >> 4) + j];
  } else if (i < kW1P + kW2P + kCP) {
    int k = i - (kW1P + kW2P);
    int j = k & 7, l = (k >> 3) & 63, ks = k >> 9;
    v = C[(l & 15) * 128 + 32 * ks + 8 * (l >> 4) + j];
  } else {
    int k = i - (kW1P + kW2P + kCP);
    int j = k & 7, l = (k >> 3) & 63, ks = k >> 9;
    v = D[(l & 15) * 64 + 32 * ks + 8 * (l >> 4) + j];
  }
  wp[i] = f2bf(v);
}

// RK45 stage-combination coefficients (dt folded in), row e = coeffs for z of stage e+2
__constant__ float CTc[5][5] = {
  {(float)(0.01 / 4.0), 0.f, 0.f, 0.f, 0.f},
  {(float)(0.01 * 3.0 / 32.0), (float)(0.01 * 9.0 / 32.0), 0.f, 0.f, 0.f},
  {(float)(0.01 * 1932.0 / 2197.0), (float)(-0.01 * 7200.0 / 2197.0), (float)(0.01 * 7296.0 / 2197.0), 0.f, 0.f},
  {(float)(0.01 * 439.0 / 216.0), (float)(-0.01 * 8.0), (float)(0.01 * 3680.0 / 513.0), (float)(-0.01 * 845.0 / 4104.0), 0.f},
  {(float)(-0.01 * 8.0 / 27.0), (float)(0.01 * 2.0), (float)(-0.01 * 3544.0 / 2565.0), (float)(0.01 * 1859.0 / 4104.0), (float)(-0.01 * 11.0 / 40.0)}
};

// tanh(x) = 1 - 2/(exp2(2x*log2 e)+1)
__device__ __forceinline__ float tanh_fast(float x) {
  float t = exp2f(x * 2.8853900817779268f);
  return 1.0f - 2.0f * __builtin_amdgcn_rcpf(t + 1.0f);
}

#define MFMA_BF16(A, B, C) __builtin_amdgcn_mfma_f32_16x16x32_bf16(A, B, C, 0, 0, 0)
#define BARRIER_LGKM do { asm volatile("s_waitcnt lgkmcnt(0)" ::: "memory"); \
                          __builtin_amdgcn_s_barrier(); } while (0)

// One block = 16 batch rows, 8 waves. Whole T-loop inside the kernel.
// Weights stream global->VGPR via 2 named 4-frag buffers (fA/fB) + 2 pinned
// chunks (W1x tile0, W2 c0): distance-2 register pipeline, uniform across
// mm1 -> mm2 -> next stage. amdgpu_waves_per_eu(2,2) grants the 256-VGPR
// budget (the R5/R11 spill was hipcc's 128-reg occupancy heuristic).
// lgkm-only barriers keep loads in flight across barriers (R5-proven safe:
// weight loads are read-only; LDS hazards drained by lgkmcnt).
// W1u*u + b1 hoisted to a once-per-step u-pass. No weight LDS traffic.
__global__ __launch_bounds__(512) __attribute__((amdgpu_waves_per_eu(2, 2)))
void rk45_kernel(const float* __restrict__ u, const float* __restrict__ x0,
                 const float* __restrict__ b1g, const float* __restrict__ b2g,
                 const unsigned short* __restrict__ wp,
                 float* __restrict__ Xout, float* __restrict__ Yout) {
  __shared__ __align__(16) unsigned short zs[16][232];   // z = [x | u] bf16
  __shared__ __align__(16) unsigned short hs[16][1048];  // h bf16 (16 x 1024)
  __shared__ __align__(16) float xs[16][132];            // master state fp32

  const int tid  = threadIdx.x;
  const int lane = tid & 63;
  const int w    = tid >> 6;     // wave 0..7
  const int r16  = lane & 15;
  const int g    = lane >> 4;    // 0..3
  const int b0   = blockIdx.x * kBT;
  const int colw = 16 * w + r16;

  const bf16x8* W1P = (const bf16x8*)wp;
  const bf16x8* W2P = (const bf16x8*)(wp + kW1P);
  const bf16x8* CP  = (const bf16x8*)(wp + kW1P + kW2P);
  const bf16x8* DP  = (const bf16x8*)(wp + kW1P + kW2P + kCP);

// 4-frag loads into named registers (x-part of W1 tile NT; W2 chunk CC)
#define LOAD_W1X(F0, F1, F2, F3, NT) do {                          \
    const bf16x8* _p = W1P + (8 * w + (NT)) * 6 * 64 + lane;       \
    F0 = _p[0]; F1 = _p[64]; F2 = _p[128]; F3 = _p[192];           \
  } while (0)
#define LOAD_W2(F0, F1, F2, F3, CC) do {                           \
    const bf16x8* _p = W2P + (w * 32 + 4 * (CC)) * 64 + lane;      \
    F0 = _p[0]; F1 = _p[64]; F2 = _p[128]; F3 = _p[192];           \
  } while (0)

  float b1r[8];
  #pragma unroll
  for (int nt = 0; nt < 8; ++nt)
    b1r[nt] = b1g[128 * w + 16 * nt + r16];
  const float b2reg = b2g[colw];

  float xreg[4];
  f32x4 ubias[8];
  f32x4 k1r = {0,0,0,0}, k2r = {0,0,0,0}, k3r = {0,0,0,0}, k4r = {0,0,0,0}, k5r = {0,0,0,0};

  #pragma unroll
  for (int q = 0; q < 4; ++q) {
    int row = 4 * g + q;
    float xv = x0[(b0 + row) * kNX + colw];
    xreg[q] = xv;
    xs[row][colw] = xv;
    zs[row][colw] = f2bf(xv);
  }

  // u prefetch (one step ahead)
  const int urow = tid >> 5, ucol = (tid & 31) * 2;
  float2 ureg = *(const float2*)&u[((b0 + urow) * kT + 0) * kNU + ucol];

  // ---- weight register pipeline: pinned chunk0s + 2 rotating buffers ----
  bf16x8 p10, p11, p12, p13;   // W1x tile 0 (pinned)
  bf16x8 p20, p21, p22, p23;   // W2 chunk 0 (pinned)
  bf16x8 fA0, fA1, fA2, fA3;   // rotating buffer A
  bf16x8 fB0, fB1, fB2, fB3;   // rotating buffer B
  LOAD_W1X(p10, p11, p12, p13, 0);
  LOAD_W2 (p20, p21, p22, p23, 0);
  LOAD_W1X(fA0, fA1, fA2, fA3, 1);
  LOAD_W1X(fB0, fB1, fB2, fB3, 2);
  __syncthreads();

  const float D1 = (float)(0.01 * 16.0 / 135.0);
  const float D3 = (float)(0.01 * 6656.0 / 12825.0);
  const float D4 = (float)(0.01 * 28561.0 / 56430.0);
  const float D5 = (float)(-0.01 * 9.0 / 50.0);
  const float D6 = (float)(0.01 * 2.0 / 55.0);

  #pragma unroll 1
  for (int t = 0; t < kT; ++t) {
    // ---- stage A: write X[t] from xs (coalesced), commit u_t, prefetch u_{t+1}
    {
      int base = tid * 4, row = base >> 7, col = base & 127;
      float4 xv = *(const float4*)&xs[row][col];
      *(float4*)&Xout[((b0 + row) * kT + t) * kNX + col] = xv;
      zs[urow][kNX + ucol]     = f2bf(ureg.x);
      zs[urow][kNX + ucol + 1] = f2bf(ureg.y);
      if (t + 1 < kT)
        ureg = *(const float2*)&u[((b0 + urow) * kT + (t + 1)) * kNU + ucol];
    }
    BARRIER_LGKM;

    // ---- u-pass (once per step): ubias[nt] = W1u-slice @ u_t + b1
    {
      bf16x8 zu0 = *(const bf16x8*)&zs[r16][8 * g + 128];
      bf16x8 zu1 = *(const bf16x8*)&zs[r16][8 * g + 160];
      #pragma unroll
      for (int nt = 0; nt < 8; ++nt) {
        int n = 8 * w + nt;
        bf16x8 uw0 = W1P[(n * 6 + 4) * 64 + lane];
        bf16x8 uw1 = W1P[(n * 6 + 5) * 64 + lane];
        float bv = b1r[nt];
        f32x4 ua = {bv, bv, bv, bv};
        ua = MFMA_BF16(zu0, uw0, ua);
        ua = MFMA_BF16(zu1, uw1, ua);
        ubias[nt] = ua;
      }
    }

    #pragma unroll 1
    for (int e = 0; e < 6; ++e) {
      // ---- matmul1: h = tanh(x-part @ W1x^T + ubias); wave w owns NH [128w,128w+128)
      bf16x8 za0 = *(const bf16x8*)&zs[r16][8 * g + 0];
      bf16x8 za1 = *(const bf16x8*)&zs[r16][8 * g + 32];
      bf16x8 za2 = *(const bf16x8*)&zs[r16][8 * g + 64];
      bf16x8 za3 = *(const bf16x8*)&zs[r16][8 * g + 96];

#define MM1(NT, F0, F1, F2, F3, ISS)                                   \
      { f32x4 aa = {0,0,0,0}, ab = {0,0,0,0};                          \
        aa = MFMA_BF16(za0, F0, aa); ab = MFMA_BF16(za1, F1, ab);      \
        aa = MFMA_BF16(za2, F2, aa); ab = MFMA_BF16(za3, F3, ab);      \
        ISS;                                                           \
        int n = 8 * w + (NT);                                          \
        _Pragma("unroll")                                              \
        for (int q = 0; q < 4; ++q) {                                  \
          float hv = tanh_fast(aa[q] + ab[q] + ubias[NT][q]);          \
          hs[4 * g + q][16 * n + r16] = f2bf(hv);                      \
        } }
      // steady-state schedule: compute c, refill the buffer 2 ahead
      MM1(0, p10, p11, p12, p13, {});
      MM1(1, fA0, fA1, fA2, fA3, LOAD_W1X(fA0, fA1, fA2, fA3, 3));
      MM1(2, fB0, fB1, fB2, fB3, LOAD_W1X(fB0, fB1, fB2, fB3, 4));
      MM1(3, fA0, fA1, fA2, fA3, LOAD_W1X(fA0, fA1, fA2, fA3, 5));
      MM1(4, fB0, fB1, fB2, fB3, LOAD_W1X(fB0, fB1, fB2, fB3, 6));
      MM1(5, fA0, fA1, fA2, fA3, LOAD_W1X(fA0, fA1, fA2, fA3, 7));
      MM1(6, fB0, fB1, fB2, fB3, LOAD_W2(fB0, fB1, fB2, fB3, 1));
      MM1(7, fA0, fA1, fA2, fA3, LOAD_W2(fA0, fA1, fA2, fA3, 2));
#undef MM1

      if (e == 0 && w == 0) {
        // y_t = x C^T + u D^T (direct global C/D loads; once per step, wave 0)
        bf16x8 zu0 = *(const bf16x8*)&zs[r16][8 * g + 128];
        bf16x8 zu1 = *(const bf16x8*)&zs[r16][8 * g + 160];
        f32x4 ay = {0,0,0,0};
        ay = MFMA_BF16(za0, CP[0 * 64 + lane], ay);
        ay = MFMA_BF16(za1, CP[1 * 64 + lane], ay);
        ay = MFMA_BF16(za2, CP[2 * 64 + lane], ay);
        ay = MFMA_BF16(za3, CP[3 * 64 + lane], ay);
        ay = MFMA_BF16(zu0, DP[lane], ay);
        ay = MFMA_BF16(zu1, DP[64 + lane], ay);
        #pragma unroll
        for (int q = 0; q < 4; ++q)
          Yout[((b0 + 4 * g + q) * kT + t) * kNY + r16] = ay[q];
      }
      BARRIER_LGKM;   // hs visible; weight loads stay in flight

      // ---- matmul2: k = h @ W2^T + b2; wave w owns NX cols [16w, 16w+16)
      f32x4 ka = {0,0,0,0}, kb = {0,0,0,0};
#define MM2(J, F0, F1, F2, F3, ISS)                                          \
      { bf16x8 h0 = *(const bf16x8*)&hs[r16][8 * g + 32 * (4 * (J) + 0)];    \
        bf16x8 h1 = *(const bf16x8*)&hs[r16][8 * g + 32 * (4 * (J) + 1)];    \
        bf16x8 h2 = *(const bf16x8*)&hs[r16][8 * g + 32 * (4 * (J) + 2)];    \
        bf16x8 h3 = *(const bf16x8*)&hs[r16][8 * g + 32 * (4 * (J) + 3)];    \
        ka = MFMA_BF16(h0, F0, ka); kb = MFMA_BF16(h1, F1, kb);              \
        ka = MFMA_BF16(h2, F2, ka); kb = MFMA_BF16(h3, F3, kb);              \
        ISS; }
      MM2(0, p20, p21, p22, p23, {});
      MM2(1, fB0, fB1, fB2, fB3, LOAD_W2(fB0, fB1, fB2, fB3, 3));
      MM2(2, fA0, fA1, fA2, fA3, LOAD_W2(fA0, fA1, fA2, fA3, 4));
      MM2(3, fB0, fB1, fB2, fB3, LOAD_W2(fB0, fB1, fB2, fB3, 5));
      MM2(4, fA0, fA1, fA2, fA3, LOAD_W2(fA0, fA1, fA2, fA3, 6));
      MM2(5, fB0, fB1, fB2, fB3, LOAD_W2(fB0, fB1, fB2, fB3, 7));
      MM2(6, fA0, fA1, fA2, fA3, LOAD_W1X(fA0, fA1, fA2, fA3, 1));  // next stage/t
      MM2(7, fB0, fB1, fB2, fB3, LOAD_W1X(fB0, fB1, fB2, fB3, 2));
#undef MM2

      f32x4 kv = ka + kb;
      #pragma unroll
      for (int q = 0; q < 4; ++q) kv[q] += b2reg;

      if      (e == 0) k1r = kv;
      else if (e == 1) k2r = kv;
      else if (e == 2) k3r = kv;
      else if (e == 3) k4r = kv;
      else if (e == 4) k5r = kv;

      if (e < 5) {
        float c1 = CTc[e][0], c2 = CTc[e][1], c3 = CTc[e][2], c4 = CTc[e][3], c5 = CTc[e][4];
        #pragma unroll
        for (int q = 0; q < 4; ++q) {
          float xt = xreg[q] + c1 * k1r[q] + c2 * k2r[q] + c3 * k3r[q] + c4 * k4r[q] + c5 * k5r[q];
          zs[4 * g + q][colw] = f2bf(xt);
        }
      } else {
        #pragma unroll
        for (int q = 0; q < 4; ++q) {
          float xn = xreg[q] + (D1 * k1r[q] + D3 * k3r[q] + D4 * k4r[q] + D5 * k5r[q] + D6 * kv[q]);
          xreg[q] = xn;
          xs[4 * g + q][colw] = xn;
          zs[4 * g + q][colw] = f2bf(xn);
        }
      }
      BARRIER_LGKM;   // zs ready for next stage's mm1
    }
  }
}

extern "C" void kernel_launch(void* const* d_in, const int* in_sizes, int n_in,
                              void* d_out, int out_size, void* d_ws, size_t ws_size,
                              hipStream_t stream) {
  const float* u  = (const float*)d_in[0];
  const float* x0 = (const float*)d_in[1];
  const float* W1 = (const float*)d_in[2];
  const float* b1 = (const float*)d_in[3];
  const float* W2 = (const float*)d_in[4];
  const float* b2 = (const float*)d_in[5];
  const float* C  = (const float*)d_in[6];
  const float* D  = (const float*)d_in[7];

  unsigned short* wp = (unsigned short*)d_ws;
  float* Xout = (float*)d_out;
  float* Yout = Xout + (size_t)512 * 256 * 128;

  hipLaunchKernelGGL(prepack_kernel, dim3((kPackTotal + 255) / 256), dim3(256), 0, stream,
                     W1, W2, C, D, wp);
  hipLaunchKernelGGL(rk45_kernel, dim3(32), dim3(512), 0, stream,
                     u, x0, b1, b2, (const unsigned short*)wp, Xout, Yout);
}